// Round 3
// baseline (1668.943 us; speedup 1.0000x reference)
//
#include <hip/hip_runtime.h>
#include <stdint.h>
#include <math.h>

// Problem constants (all fp32 per reference)
#define TT 256
#define BB 256
#define II 9
#define HH 1024
#define AAx 4
#define RR 38
#define BH (BB*HH)
#define NJB 16          // col-blocks per row-group (64 cols each)

typedef __attribute__((ext_vector_type(8))) short short8;
typedef __attribute__((ext_vector_type(4))) float f32x4;
typedef __attribute__((ext_vector_type(4))) unsigned int u32x4;

// Packed-bf16 shadow state (double-buffered by t parity). Static __device__
// allocation: no dependence on ws_size (v3's workspace write was the likely
// container-killer if ws_size < 2.1 MB).
__device__ unsigned g_shadow[2*BH];

__device__ __forceinline__ float bf2f(unsigned short u){
  union{unsigned int i; float f;} v; v.i = ((unsigned int)u)<<16; return v.f;
}
__device__ __forceinline__ unsigned short f2bf(float f){
  union{float f; unsigned int i;} v; v.f = f;
  unsigned int r = (v.i + 0x7FFFu + ((v.i>>16)&1u)) >> 16;
  return (unsigned short)r;
}

// Coherent (cross-XCD) 16B load pair from the packed-bf16 shadow state:
// bypass L1+L2 (sc0 sc1), served from MALL. Per-access coherence instead of
// cache-wide acquire fences.
#define ISSUE2(d0,d1,s0,s1)                                                   \
  asm volatile("global_load_dwordx4 %0, %2, off offset:" s0 " sc0 sc1\n\t"    \
               "global_load_dwordx4 %1, %2, off offset:" s1 " sc0 sc1"        \
               : "=&v"(d0), "=&v"(d1) : "v"(ap) : "memory")

// Counted wait that DEFINES the two quads it makes ready ("+v" ties) so the
// dependent unpack/MFMA cannot be hoisted above it (rule #18 hazard).
#define WAITP(n,q0,q1)                                                        \
  asm volatile("s_waitcnt vmcnt(" n ")" : "+v"(q0), "+v"(q1) :: "memory")

// Coherent write-through store for the shadow state (release side handled by
// vmcnt(0) drain + relaxed agent atomic counter; no buffer_wbl2 needed).
#define STORE_U32(p,x)                                                        \
  asm volatile("global_store_dword %0, %1, off sc0 sc1" :: "v"(p), "v"(x) : "memory")

// Persistent fp32 RNN.
// Grid: 256 blocks = 16 row-groups (g=bid&15, 16 batch rows) x 16 col-blocks
// (jb=bid>>4, 64 cols). Block: 512 threads = 8 waves; wave w owns K-slice
// [128w,128w+128) of h2h, register-stationary as hi/lo split-bf16 MFMA
// B-fragments. 3-term MFMA (ah*Bh + al*Bh + ah*Bl) => ~2^-17 rel GEMM error.
// v2: per-access sc0|sc1 coherence replaced cache-wide agent fences (2.1x).
// v3: producer-side bf16 split — epilogue stores packed (lo<<16|hi) shadow
//     state (double-buffered by t parity); consumers unpack with v_perm_b32
//     (8 ops/ki) instead of re-splitting fp32 (~112 ops/ki, and 16x redundant
//     across col-blocks). out becomes plain cached stores. State loads 4-deep
//     pipelined (counted vmcnt 6/4/2/0); inp/act staging prefetched a step
//     ahead.
// v4: shadow moved from d_ws (size unknown -> possible OOB crash) to a
//     static __device__ global.
__global__ __launch_bounds__(512, 2) void rnn_persist(
    const float* __restrict__ inp,  const float* __restrict__ hid0,
    const float* __restrict__ act,  const float* __restrict__ rew,
    const float* __restrict__ i2h,  const float* __restrict__ h2h,
    const float* __restrict__ a2h,  const float* __restrict__ r2h,
    const float* __restrict__ bh,   const float* __restrict__ rr,
    const int*   __restrict__ kact_p,
    float* __restrict__ out, int* __restrict__ cnt)
{
  __shared__ f32x4 part[8*4*64];            // 32 KB K-split partials
  __shared__ unsigned short sexth[16*32];   // 1 KB ext-A hi (inp|act|0)
  __shared__ unsigned short sextl[16*32];   // 1 KB ext-A lo

  const int tid   = threadIdx.x;
  const int w     = tid >> 6;
  const int l     = tid & 63;
  const int row16 = l & 15;
  const int quad  = l >> 4;
  const int g     = blockIdx.x & 15;   // row-group (16 rows)
  const int jb    = blockIdx.x >> 4;   // col-block (64 cols)

  const float kact = (float)kact_p[0];

  // ---- register-stationary hi/lo B-fragments of h2h ----
  short8 wbh[4][4], wbl[4][4];
  #pragma unroll
  for (int ki=0; ki<4; ki++){
    const int kb = w*128 + ki*32 + quad*8;
    #pragma unroll
    for (int nt=0; nt<4; nt++){
      const int n = jb*64 + nt*16 + row16;
      short8 vh, vl;
      #pragma unroll
      for (int j=0; j<8; j++){
        const float bv = h2h[(size_t)(kb+j)*HH + n];
        const unsigned short hh = f2bf(bv);
        vh[j] = (short)hh;
        vl[j] = (short)f2bf(bv - bf2f(hh));
      }
      wbh[ki][nt] = vh; wbl[ki][nt] = vl;
    }
  }
  // ext B-fragments (wave 0 only): k<9 = i2h, 9..12 = kact*a2h, rest 0
  short8 webh[4], webl[4];
  #pragma unroll
  for (int nt=0; nt<4; nt++){
    short8 vh, vl;
    #pragma unroll
    for (int j=0; j<8; j++){
      const int k = quad*8 + j;
      const int n = jb*64 + nt*16 + row16;
      float bv = 0.f;
      if (w == 0){
        if (k < II)          bv = i2h[(size_t)k*HH + n];
        else if (k < II+AAx) bv = kact * a2h[(size_t)(k-II)*HH + n];
      }
      const unsigned short hh = f2bf(bv);
      vh[j] = (short)hh;
      vl[j] = (short)f2bf(bv - bf2f(hh));
    }
    webh[nt] = vh; webl[nt] = vl;
  }

  // ---- epilogue constants (waves 0..3 own cols; w>=4 would be OOB) ----
  const int ecol = jb*64 + w*16 + row16;
  float r_own = 0.f, romr = 0.f;
  float h_own[4] = {0,0,0,0}, rb[4] = {0,0,0,0};
  if (w < 4){
    r_own = rr[ecol];
    romr  = 1.f - r_own;
    #pragma unroll
    for (int i=0; i<4; i++){
      const int br = 16*g + 4*quad + i;
      h_own[i] = hid0[(size_t)br*HH + ecol];
      float s = bh[ecol];
      for (int q=0; q<RR; q++) s += rew[(size_t)br*RR + q] * r2h[(size_t)q*HH + ecol];
      rb[i] = s;
    }
  }

  // sext zero-init (k in [13,32) stays 0) + staging index precompute
  sexth[tid] = 0; sextl[tid] = 0;
  const int st_act = (tid < 16*13);
  const int st_row = st_act ? (tid / 13) : 0;
  const int st_q   = st_act ? (tid % 13) : 0;

  // prefetch t=0 inp/act staging value
  float xv_cur = 0.f, xv_nxt = 0.f;
  if (st_act){
    const int br = 16*g + st_row;
    xv_cur = (st_q < II) ? inp[(size_t)br*II + st_q]
                         : act[(size_t)br*AAx + (st_q - II)];
  }

  // ---- shadow-init: split hid0 into packed bf16 shadow buf[1] ----
  if (w < 4){
    unsigned* shW = g_shadow + (size_t)BH;   // buf[1]
    #pragma unroll
    for (int i=0; i<4; i++){
      const int br = 16*g + 4*quad + i;
      const float hv = h_own[i];
      const unsigned hh = f2bf(hv);
      const unsigned hl = f2bf(hv - bf2f((unsigned short)hh));
      const unsigned pk = (hl<<16) | hh;
      STORE_U32(shW + (size_t)br*HH + ecol, pk);
    }
  }
  asm volatile("s_waitcnt vmcnt(0)" ::: "memory");
  __syncthreads();
  if (tid == 0){
    __hip_atomic_fetch_add(&cnt[g*32], 1, __ATOMIC_RELAXED, __HIP_MEMORY_SCOPE_AGENT);
    while (__hip_atomic_load(&cnt[g*32], __ATOMIC_RELAXED, __HIP_MEMORY_SCOPE_AGENT) < NJB)
      __builtin_amdgcn_s_sleep(1);
  }
  __syncthreads();

  const int arow = 16*g + row16;

  for (int t=0; t<TT; t++){
    // stage this step's inp/act slice (hi/lo) into LDS from prefetched reg
    if (st_act){
      const unsigned short hh = f2bf(xv_cur);
      sexth[st_row*32 + st_q] = hh;
      sextl[st_row*32 + st_q] = f2bf(xv_cur - bf2f(hh));
    }
    __syncthreads();

    // packed shadow of h(t-1): buf[(t+1)&1]
    const unsigned* ap = g_shadow + (size_t)((t+1)&1)*BH
                       + (size_t)arow*HH + (size_t)w*128 + quad*8;

    f32x4 acc[4];
    #pragma unroll
    for (int nt=0; nt<4; nt++){ acc[nt].x=0.f; acc[nt].y=0.f; acc[nt].z=0.f; acc[nt].w=0.f; }

    // one ki: unpack packed (lo<<16|hi) u32s via v_perm, then 12 MFMAs
    auto doKi = [&](int ki, const u32x4& q0, const u32x4& q1){
      short8 ah, al;
      unsigned* ahp = (unsigned*)&ah;
      unsigned* alp = (unsigned*)&al;
      #pragma unroll
      for (int j=0; j<2; j++){
        ahp[j]   = __builtin_amdgcn_perm(q0[2*j+1], q0[2*j], 0x05040100u);
        alp[j]   = __builtin_amdgcn_perm(q0[2*j+1], q0[2*j], 0x07060302u);
        ahp[2+j] = __builtin_amdgcn_perm(q1[2*j+1], q1[2*j], 0x05040100u);
        alp[2+j] = __builtin_amdgcn_perm(q1[2*j+1], q1[2*j], 0x07060302u);
      }
      #pragma unroll
      for (int nt=0; nt<4; nt++){
        acc[nt] = __builtin_amdgcn_mfma_f32_16x16x32_bf16(ah, wbh[ki][nt], acc[nt], 0,0,0);
        acc[nt] = __builtin_amdgcn_mfma_f32_16x16x32_bf16(al, wbh[ki][nt], acc[nt], 0,0,0);
        acc[nt] = __builtin_amdgcn_mfma_f32_16x16x32_bf16(ah, wbl[ki][nt], acc[nt], 0,0,0);
      }
    };

    // 4-deep pipelined coherent state loads; counted waits 6/4/2/0.
    {
      u32x4 p0,p1,p2,p3,p4,p5,p6,p7;
      ISSUE2(p0,p1,"0","16");      // ki=0
      ISSUE2(p2,p3,"128","144");   // ki=1
      ISSUE2(p4,p5,"256","272");   // ki=2
      ISSUE2(p6,p7,"384","400");   // ki=3
      // prefetch next step's inp/act into regs (plain cached loads; issued
      // after the asm block so they are the newest vmcnt entries)
      if (st_act && (t+1 < TT)){
        const int br = 16*g + st_row;
        xv_nxt = (st_q < II) ? inp[((size_t)(t+1)*BB + br)*II + st_q]
                             : act[((size_t)(t+1)*BB + br)*AAx + (st_q - II)];
      }
      WAITP("6",p0,p1); doKi(0,p0,p1);
      WAITP("4",p2,p3); doKi(1,p2,p3);
      WAITP("2",p4,p5); doKi(2,p4,p5);
      WAITP("0",p6,p7); doKi(3,p6,p7);
    }

    // ext contribution (wave 0): inp@i2h + kact*(act@a2h), hi/lo both sides
    if (w == 0){
      const short8 aeh = *(const short8*)&sexth[row16*32 + quad*8];
      const short8 ael = *(const short8*)&sextl[row16*32 + quad*8];
      #pragma unroll
      for (int nt=0; nt<4; nt++){
        acc[nt] = __builtin_amdgcn_mfma_f32_16x16x32_bf16(aeh, webh[nt], acc[nt], 0,0,0);
        acc[nt] = __builtin_amdgcn_mfma_f32_16x16x32_bf16(ael, webh[nt], acc[nt], 0,0,0);
        acc[nt] = __builtin_amdgcn_mfma_f32_16x16x32_bf16(aeh, webl[nt], acc[nt], 0,0,0);
      }
    }

    // K-split reduction through LDS
    #pragma unroll
    for (int nt=0; nt<4; nt++) part[(w*4 + nt)*64 + l] = acc[nt];
    __syncthreads();

    if (w < 4){
      f32x4 z = part[(0*4 + w)*64 + l];
      #pragma unroll
      for (int s=1; s<8; s++){
        const f32x4 p = part[(s*4 + w)*64 + l];
        z.x += p.x; z.y += p.y; z.z += p.z; z.w += p.w;
      }
      unsigned* shW = g_shadow + (size_t)(t&1)*BH;
      const float zz[4] = {z.x, z.y, z.z, z.w};
      #pragma unroll
      for (int i=0; i<4; i++){
        const float x  = zz[i] + rb[i];
        const float hc = tanhf(x);
        const float hn = romr*hc + r_own*h_own[i];
        h_own[i] = hn;
        const int br = 16*g + 4*quad + i;
        out[(size_t)t*BH + (size_t)br*HH + ecol] = hn;   // plain cached store
        const unsigned hh = f2bf(hn);
        const unsigned hl = f2bf(hn - bf2f((unsigned short)hh));
        STORE_U32(shW + (size_t)br*HH + ecol, (hl<<16)|hh);
      }
    }

    // row-group barrier (16 col-blocks): drain sc1 shadow stores, then
    // relaxed agent counter. Targets shifted by +NJB for the init round.
    asm volatile("s_waitcnt vmcnt(0)" ::: "memory");
    __syncthreads();
    if (tid == 0){
      __hip_atomic_fetch_add(&cnt[g*32], 1, __ATOMIC_RELAXED, __HIP_MEMORY_SCOPE_AGENT);
      const int target = NJB*(t+2);
      while (__hip_atomic_load(&cnt[g*32], __ATOMIC_RELAXED, __HIP_MEMORY_SCOPE_AGENT) < target)
        __builtin_amdgcn_s_sleep(1);
    }
    __syncthreads();

    xv_cur = xv_nxt;
  }
}

extern "C" void kernel_launch(void* const* d_in, const int* in_sizes, int n_in,
                              void* d_out, int out_size, void* d_ws, size_t ws_size,
                              hipStream_t stream) {
  const float* inp  = (const float*)d_in[0];
  const float* hid0 = (const float*)d_in[1];
  const float* act  = (const float*)d_in[2];
  const float* rew  = (const float*)d_in[3];
  const float* i2h  = (const float*)d_in[4];
  const float* h2h  = (const float*)d_in[5];
  const float* a2h  = (const float*)d_in[6];
  const float* r2h  = (const float*)d_in[7];
  const float* bh   = (const float*)d_in[8];
  const float* rr   = (const float*)d_in[9];
  const int*   kact = (const int*)d_in[10];
  float* out = (float*)d_out;

  int* cnt = (int*)d_ws;   // 16 groups x 128 B counters (4 KB only)
  hipMemsetAsync(d_ws, 0, 4096, stream);

  rnn_persist<<<256, 512, 0, stream>>>(inp, hid0, act, rew, i2h, h2h, a2h, r2h,
                                       bh, rr, kact, out, cnt);
}

// Round 6
// 1259.398 us; speedup vs baseline: 1.3252x; 1.3252x over previous
//
#include <hip/hip_runtime.h>
#include <stdint.h>
#include <math.h>

// Problem constants (all fp32 per reference)
#define TT 256
#define BB 256
#define II 9
#define HH 1024
#define AAx 4
#define RR 38
#define BH (BB*HH)
#define NJB 16          // col-blocks per row-group (64 cols each)

typedef __attribute__((ext_vector_type(8))) short short8;
typedef __attribute__((ext_vector_type(4))) float f32x4;
typedef __attribute__((ext_vector_type(4))) unsigned int u32x4;

__device__ __forceinline__ float bf2f(unsigned short u){
  union{unsigned int i; float f;} v; v.i = ((unsigned int)u)<<16; return v.f;
}
__device__ __forceinline__ unsigned short f2bf(float f){
  union{float f; unsigned int i;} v; v.f = f;
  unsigned int r = (v.i + 0x7FFFu + ((v.i>>16)&1u)) >> 16;
  return (unsigned short)r;
}

// Coherent (cross-XCD) 16B load pair: bypass L1+L2 (sc0 sc1), served from
// MALL. Per-access coherence instead of cache-wide acquire fences. This is
// the ONLY protocol that has passed on this hardware (v2); v5/v6's same-XCD
// sc0-only fast path FAILED correctness (absmax 0.438) despite a passing
// visibility probe — retired.
#define ISSUE2(d0,d1,s0,s1)                                                   \
  asm volatile("global_load_dwordx4 %0, %2, off offset:" s0 " sc0 sc1\n\t"    \
               "global_load_dwordx4 %1, %2, off offset:" s1 " sc0 sc1"        \
               : "=&v"(d0), "=&v"(d1) : "v"(ap) : "memory")

// Counted wait that DEFINES the two quads it makes ready ("+v" ties) so the
// dependent split/MFMA cannot be hoisted above it (rule #18 hazard).
#define WAITP(n,q0,q1)                                                        \
  asm volatile("s_waitcnt vmcnt(" n ")" : "+v"(q0), "+v"(q1) :: "memory")

// Coherent write-through store (release side handled by vmcnt(0) drain +
// relaxed agent atomic counter; no buffer_wbl2 needed).
#define STORE_CC(p,x)                                                         \
  asm volatile("global_store_dword %0, %1, off sc0 sc1" :: "v"(p), "v"(x) : "memory")

// RNE f32 pair -> packed 2xbf16 (no builtin on gfx950; inline asm per m240)
#define CVTPK(d,s0,s1)                                                        \
  asm("v_cvt_pk_bf16_f32 %0, %1, %2" : "=v"(d) : "v"(s0), "v"(s1))

// Persistent fp32 RNN.
// Grid: 256 blocks = 16 row-groups (g=bid&15, 16 batch rows) x 16 col-blocks
// (jb=bid>>4, 64 cols). Block: 512 threads = 8 waves; wave w owns K-slice
// [128w,128w+128) of h2h, register-stationary as hi/lo split-bf16 MFMA
// B-fragments. 3-term MFMA (ah*Bh + al*Bh + ah*Bl) => ~2^-17 rel GEMM error.
// v2 (1372us, PASSED): per-access sc0|sc1 coherence + relaxed agent counter.
// v3/v4 (1669us, REVERTED): producer-side shadow split lengthened the
//     store->drain->barrier->load critical path.
// v5/v6 (FAILED, RETIRED): same-XCD sc0-only fast path — wrong results even
//     with a passing L2-visibility probe; scope model wrong somewhere.
// v7: v2 protocol exactly, plus (a) v_cvt_pk_bf16_f32 split in doKi: hi=RNE
//     pair-converted (4 ops), lo = exact Sterbenz residual (8 ops) RNE-packed
//     (4 ops) => 24 VALU/ki vs 56, lo exact before rounding so accuracy >= v2;
//     (b) single-load next-step inp/act prefetch pinned between asm blocks
//     (ledger-exact counted waits 2/2/3/1).
__global__ __launch_bounds__(512, 2) void rnn_persist(
    const float* __restrict__ inp,  const float* __restrict__ hid0,
    const float* __restrict__ act,  const float* __restrict__ rew,
    const float* __restrict__ i2h,  const float* __restrict__ h2h,
    const float* __restrict__ a2h,  const float* __restrict__ r2h,
    const float* __restrict__ bh,   const float* __restrict__ rr,
    const int*   __restrict__ kact_p,
    float* __restrict__ out, int* __restrict__ cnt)
{
  __shared__ f32x4 part[8*4*64];            // 32 KB K-split partials
  __shared__ unsigned short sexth[16*32];   // 1 KB ext-A hi (inp|act|0)
  __shared__ unsigned short sextl[16*32];   // 1 KB ext-A lo

  const int tid   = threadIdx.x;
  const int w     = tid >> 6;
  const int l     = tid & 63;
  const int row16 = l & 15;
  const int quad  = l >> 4;
  const int g     = blockIdx.x & 15;   // row-group (16 rows)
  const int jb    = blockIdx.x >> 4;   // col-block (64 cols)

  const float kact = (float)kact_p[0];

  // ---- register-stationary hi/lo B-fragments of h2h ----
  short8 wbh[4][4], wbl[4][4];
  #pragma unroll
  for (int ki=0; ki<4; ki++){
    const int kb = w*128 + ki*32 + quad*8;
    #pragma unroll
    for (int nt=0; nt<4; nt++){
      const int n = jb*64 + nt*16 + row16;
      short8 vh, vl;
      #pragma unroll
      for (int j=0; j<8; j++){
        const float bv = h2h[(size_t)(kb+j)*HH + n];
        const unsigned short hh = f2bf(bv);
        vh[j] = (short)hh;
        vl[j] = (short)f2bf(bv - bf2f(hh));
      }
      wbh[ki][nt] = vh; wbl[ki][nt] = vl;
    }
  }
  // ext B-fragments (wave 0 only): k<9 = i2h, 9..12 = kact*a2h, rest 0
  short8 webh[4], webl[4];
  #pragma unroll
  for (int nt=0; nt<4; nt++){
    short8 vh, vl;
    #pragma unroll
    for (int j=0; j<8; j++){
      const int k = quad*8 + j;
      const int n = jb*64 + nt*16 + row16;
      float bv = 0.f;
      if (w == 0){
        if (k < II)          bv = i2h[(size_t)k*HH + n];
        else if (k < II+AAx) bv = kact * a2h[(size_t)(k-II)*HH + n];
      }
      const unsigned short hh = f2bf(bv);
      vh[j] = (short)hh;
      vl[j] = (short)f2bf(bv - bf2f(hh));
    }
    webh[nt] = vh; webl[nt] = vl;
  }

  // ---- epilogue constants (waves 0..3 own cols; w>=4 would be OOB) ----
  const int ecol = jb*64 + w*16 + row16;
  float r_own = 0.f, romr = 0.f;
  float h_own[4] = {0,0,0,0}, rb[4] = {0,0,0,0};
  if (w < 4){
    r_own = rr[ecol];
    romr  = 1.f - r_own;
    #pragma unroll
    for (int i=0; i<4; i++){
      const int br = 16*g + 4*quad + i;
      h_own[i] = hid0[(size_t)br*HH + ecol];
      float s = bh[ecol];
      for (int q=0; q<RR; q++) s += rew[(size_t)br*RR + q] * r2h[(size_t)q*HH + ecol];
      rb[i] = s;
    }
  }

  // sext zero-init (k in [13,32) stays 0) + staging index precompute
  sexth[tid] = 0; sextl[tid] = 0;
  const int st_act = (tid < 16*13);
  const int st_row = st_act ? (tid / 13) : 0;
  const int st_q   = st_act ? (tid % 13) : 0;
  __syncthreads();

  // prefetch t=0 inp/act staging value
  float xv_cur = 0.f, xv_nxt = 0.f;
  if (st_act){
    const int br = 16*g + st_row;
    xv_cur = (st_q < II) ? inp[(size_t)br*II + st_q]
                         : act[(size_t)br*AAx + (st_q - II)];
  }

  const int arow = 16*g + row16;

  for (int t=0; t<TT; t++){
    // stage this step's inp/act slice (hi/lo) into LDS from prefetched reg
    if (st_act){
      const unsigned short hh = f2bf(xv_cur);
      sexth[st_row*32 + st_q] = hh;
      sextl[st_row*32 + st_q] = f2bf(xv_cur - bf2f(hh));
    }
    __syncthreads();

    const float* __restrict__ hp = t ? (out + (size_t)(t-1)*BH) : hid0;
    const float* ap = hp + (size_t)arow*HH + (size_t)w*128 + quad*8;

    f32x4 acc[4];
    #pragma unroll
    for (int nt=0; nt<4; nt++){ acc[nt].x=0.f; acc[nt].y=0.f; acc[nt].z=0.f; acc[nt].w=0.f; }

    // one ki: cvt_pk hi/lo split (24 VALU) + 12 MFMAs (ki is a literal).
    // hi = RNE bf16 (v_cvt_pk); lo = f - hi_f32 is EXACT (Sterbenz: hi
    // within 2^-8 of f), then RNE-packed => split error <= v2's.
    auto doKi = [&](int ki, const f32x4& q0, const f32x4& q1){
      u32x4 ahw, alw;
      CVTPK(ahw[0], q0[0], q0[1]);
      CVTPK(ahw[1], q0[2], q0[3]);
      CVTPK(ahw[2], q1[0], q1[1]);
      CVTPK(ahw[3], q1[2], q1[3]);
      const float l0 = q0[0] - __builtin_bit_cast(float, ahw[0] << 16);
      const float l1 = q0[1] - __builtin_bit_cast(float, ahw[0] & 0xFFFF0000u);
      const float l2 = q0[2] - __builtin_bit_cast(float, ahw[1] << 16);
      const float l3 = q0[3] - __builtin_bit_cast(float, ahw[1] & 0xFFFF0000u);
      const float l4 = q1[0] - __builtin_bit_cast(float, ahw[2] << 16);
      const float l5 = q1[1] - __builtin_bit_cast(float, ahw[2] & 0xFFFF0000u);
      const float l6 = q1[2] - __builtin_bit_cast(float, ahw[3] << 16);
      const float l7 = q1[3] - __builtin_bit_cast(float, ahw[3] & 0xFFFF0000u);
      CVTPK(alw[0], l0, l1);
      CVTPK(alw[1], l2, l3);
      CVTPK(alw[2], l4, l5);
      CVTPK(alw[3], l6, l7);
      const short8 ah = __builtin_bit_cast(short8, ahw);
      const short8 al = __builtin_bit_cast(short8, alw);
      #pragma unroll
      for (int nt=0; nt<4; nt++){
        acc[nt] = __builtin_amdgcn_mfma_f32_16x16x32_bf16(ah, wbh[ki][nt], acc[nt], 0,0,0);
        acc[nt] = __builtin_amdgcn_mfma_f32_16x16x32_bf16(al, wbh[ki][nt], acc[nt], 0,0,0);
        acc[nt] = __builtin_amdgcn_mfma_f32_16x16x32_bf16(ah, wbl[ki][nt], acc[nt], 0,0,0);
      }
    };

    // 2-deep pipelined coherent state loads. vmcnt ledger (oldest-first):
    // [k0,k0] +[k1,k1] -> W(2): k0 ready -> +[k2,k2] -> W(2): k1 ready
    // -> +[k3,k3] + 1 prefetch load -> W(3): k2 ready -> W(1): k3 ready,
    // prefetch may stay in flight (drained by the epilogue vmcnt(0)).
    {
      f32x4 p0,p1,q0,q1;
      ISSUE2(p0,p1,"0","16");      // ki=0
      ISSUE2(q0,q1,"128","144");   // ki=1
      WAITP("2",p0,p1);
      doKi(0,p0,p1);
      ISSUE2(p0,p1,"256","272");   // ki=2
      WAITP("2",q0,q1);
      doKi(1,q0,q1);
      ISSUE2(q0,q1,"384","400");   // ki=3
      // next-step inp/act prefetch: SINGLE load (pointer-select, no branch)
      // pinned here by the surrounding "memory"-clobber asm => ledger-exact.
      {
        const int tt2 = (t+1 < TT) ? (t+1) : (TT-1);
        const int br  = 16*g + st_row;
        const float* xp = st_act
          ? ((st_q < II) ? inp + ((size_t)tt2*BB + br)*II  + st_q
                         : act + ((size_t)tt2*BB + br)*AAx + (st_q - II))
          : inp;
        xv_nxt = *xp;
      }
      WAITP("3",p0,p1);
      doKi(2,p0,p1);
      WAITP("1",q0,q1);
      doKi(3,q0,q1);
    }

    // ext contribution (wave 0): inp@i2h + kact*(act@a2h), hi/lo both sides
    if (w == 0){
      const short8 aeh = *(const short8*)&sexth[row16*32 + quad*8];
      const short8 ael = *(const short8*)&sextl[row16*32 + quad*8];
      #pragma unroll
      for (int nt=0; nt<4; nt++){
        acc[nt] = __builtin_amdgcn_mfma_f32_16x16x32_bf16(aeh, webh[nt], acc[nt], 0,0,0);
        acc[nt] = __builtin_amdgcn_mfma_f32_16x16x32_bf16(ael, webh[nt], acc[nt], 0,0,0);
        acc[nt] = __builtin_amdgcn_mfma_f32_16x16x32_bf16(aeh, webl[nt], acc[nt], 0,0,0);
      }
    }

    // K-split reduction through LDS
    #pragma unroll
    for (int nt=0; nt<4; nt++) part[(w*4 + nt)*64 + l] = acc[nt];
    __syncthreads();

    if (w < 4){
      f32x4 z = part[(0*4 + w)*64 + l];
      #pragma unroll
      for (int s=1; s<8; s++){
        const f32x4 p = part[(s*4 + w)*64 + l];
        z.x += p.x; z.y += p.y; z.z += p.z; z.w += p.w;
      }
      const float zz[4] = {z.x, z.y, z.z, z.w};
      #pragma unroll
      for (int i=0; i<4; i++){
        const float x  = zz[i] + rb[i];
        const float hc = tanhf(x);
        const float hn = romr*hc + r_own*h_own[i];
        h_own[i] = hn;
        const int br = 16*g + 4*quad + i;
        float* op = out + (size_t)t*BH + (size_t)br*HH + ecol;
        STORE_CC(op, hn);            // write-through to coherence point
      }
    }

    // row-group barrier (16 col-blocks): drain sc1 stores (also drains the
    // prefetch), then relaxed agent counter. Proven v2 protocol.
    asm volatile("s_waitcnt vmcnt(0)" ::: "memory");
    __syncthreads();
    if (tid == 0){
      __hip_atomic_fetch_add(&cnt[g*32], 1, __ATOMIC_RELAXED, __HIP_MEMORY_SCOPE_AGENT);
      const int target = NJB*(t+1);
      while (__hip_atomic_load(&cnt[g*32], __ATOMIC_RELAXED, __HIP_MEMORY_SCOPE_AGENT) < target)
        __builtin_amdgcn_s_sleep(1);
    }
    __syncthreads();

    xv_cur = xv_nxt;
  }
}

extern "C" void kernel_launch(void* const* d_in, const int* in_sizes, int n_in,
                              void* d_out, int out_size, void* d_ws, size_t ws_size,
                              hipStream_t stream) {
  const float* inp  = (const float*)d_in[0];
  const float* hid0 = (const float*)d_in[1];
  const float* act  = (const float*)d_in[2];
  const float* rew  = (const float*)d_in[3];
  const float* i2h  = (const float*)d_in[4];
  const float* h2h  = (const float*)d_in[5];
  const float* a2h  = (const float*)d_in[6];
  const float* r2h  = (const float*)d_in[7];
  const float* bh   = (const float*)d_in[8];
  const float* rr   = (const float*)d_in[9];
  const int*   kact = (const int*)d_in[10];
  float* out = (float*)d_out;

  int* cnt = (int*)d_ws;   // 16 groups x 128 B counters (4 KB only)
  hipMemsetAsync(d_ws, 0, 4096, stream);

  rnn_persist<<<256, 512, 0, stream>>>(inp, hid0, act, rew, i2h, h2h, a2h, r2h,
                                       bh, rr, kact, out, cnt);
}